// Round 6
// baseline (1271.187 us; speedup 1.0000x reference)
//
#include <hip/hip_runtime.h>
#include <stdint.h>

// ---------------------------------------------------------------------------
// FakeNewsModel: 3-layer GraphSAGE (mean agg), N=50000, E=1.6M, width 64.
// Round 6: self-correcting MFMA k_project.
//   k_cal v2: 32 indicator-MFMA probes recover the full relative A/B k-slot
//   permutation pi; one product probe pins the C layout (4 variants).
//   k_prepw bakes pi into WT. k_verify spot-checks h0 vs scalar recompute;
//   k_fixup (always launched) overwrites h0 with scalar projection if the
//   check tripped. Pass guaranteed in every world; counters reveal which.
// ---------------------------------------------------------------------------

typedef __attribute__((ext_vector_type(8))) unsigned short u16x8;
typedef __attribute__((ext_vector_type(8))) short bf16x8;
typedef __attribute__((ext_vector_type(4))) float f32x4;

static __device__ __forceinline__ float bf2f(unsigned short u) {
  union { unsigned int i; float f; } v;
  v.i = ((unsigned int)u) << 16;
  return v.f;
}

static __device__ __forceinline__ unsigned short f2bf(float f) {
  union { float f; unsigned int i; } v;
  v.f = f;
  unsigned int u = v.i;
  unsigned int r = (u + 0x7FFFu + ((u >> 16) & 1u)) >> 16;  // RNE
  return (unsigned short)r;
}

template <bool BF>
static __device__ __forceinline__ float ldf(const void* p, long long i) {
  if (BF) return bf2f(((const unsigned short*)p)[i]);
  return ((const float*)p)[i];
}

template <bool BF>
static __device__ __forceinline__ void load8(const void* p, long long idx,
                                             float* out) {
  if (BF) {
    u16x8 v = *(const u16x8*)((const unsigned short*)p + idx);
#pragma unroll
    for (int j = 0; j < 8; ++j) out[j] = bf2f(v[j]);
  } else {
    f32x4 a = *(const f32x4*)((const float*)p + idx);
    f32x4 b = *(const f32x4*)((const float*)p + idx + 4);
#pragma unroll
    for (int j = 0; j < 4; ++j) {
      out[j] = a[j];
      out[4 + j] = b[j];
    }
  }
}

template <bool BF>
static __device__ __forceinline__ void loadw2(const void* p, long long idx,
                                              float& w0, float& w1) {
  if (BF) {
    unsigned int u = *(const unsigned int*)((const unsigned short*)p + idx);
    union { unsigned int i; float f; } c0, c1;
    c0.i = u << 16;
    c1.i = u & 0xFFFF0000u;
    w0 = c0.f;
    w1 = c1.f;
  } else {
    const float* f = (const float*)p + idx;
    w0 = f[0];
    w1 = f[1];
  }
}

static __device__ __forceinline__ int clampN(int v, int N) {
  return v < 0 ? 0 : (v >= N ? N - 1 : v);
}

// ---------------- dtype detection ----------------
__global__ void k_detect(const void* Wp, const int* ei, int* flags) {
  if (threadIdx.x == 0 && blockIdx.x == 0) {
    const unsigned short* w = (const unsigned short*)Wp;
    int bf = 1;
    for (int i = 0; i < 64; ++i) {
      float v = fabsf(bf2f(w[i]));
      if (!(v < 1.0f)) bf = 0;  // catches NaN too
    }
    flags[0] = bf;
    int i64 = 1;
    for (int i = 0; i < 32; ++i)
      if (ei[2 * i + 1] != 0) i64 = 0;
    flags[1] = i64;
    flags[3] = 0;  // verify-failure latch (ws is poisoned each launch)
  }
}

// ---------------- MFMA layout calibration v2 ----------------
// Structural assumptions: A's m = lane&15, B's n covers 0..15 via lane&15
// (any lane bijection ok for step 1), k = g(quad,slot) for unknown bijections
// g_A, g_B. Step 1 recovers pi[p] = g_A^-1(g_B(p)) (the only thing that
// matters for product correctness). Step 2 pins the C/D layout among 4
// variants using an asymmetric exact-integer product. Any anomaly -> -1.
static __device__ __forceinline__ int amat(int m, int k) {
  return ((m * 7 + k * 3 + ((m * k) & 7)) % 9) - 4;
}
static __device__ __forceinline__ int bmatv(int k, int n) {
  return ((k * 5 + n * 11 + ((k * n) & 7)) % 9) - 4;
}

__global__ void k_cal(int* flags) {
  int lane = (int)threadIdx.x;  // <<<1, 64>>>
  int quad = lane >> 4, low = lane & 15;
  f32x4 zero = {0.f, 0.f, 0.f, 0.f};
  int pi[32];
  bool ok = true;
  for (int p0 = 0; p0 < 32; ++p0) {
    int q0 = p0 >> 3, s0 = p0 & 7;
    bf16x8 af, bfr;
#pragma unroll
    for (int s = 0; s < 8; ++s) {
      af[s] = (short)f2bf((float)(quad * 8 + s + 1));
      bfr[s] = (short)f2bf((quad == q0 && s == s0) ? 1.0f : 0.0f);
    }
    f32x4 d = __builtin_amdgcn_mfma_f32_16x16x32_bf16(af, bfr, zero, 0, 0, 0);
    // D must be uniform = enc(A-position sharing B-position p0's k)
    float v0 = d[0];
    bool u = (d[1] == v0) && (d[2] == v0) && (d[3] == v0);
    float vb = __uint_as_float(
        __builtin_amdgcn_readfirstlane(__float_as_uint(v0)));
    u = u && (v0 == vb);
    ok = ok && (__ballot(u) == ~0ull);
    int p = (int)vb - 1;
    ok = ok && (p >= 0 && p < 32);
    pi[p0] = (p >= 0 && p < 32) ? p : 0;
  }
  unsigned int mask = 0;
  for (int p0 = 0; p0 < 32; ++p0) mask |= (1u << pi[p0]);
  ok = ok && (mask == 0xFFFFFFFFu);

  int cvar = -1;
  if (ok) {
    bf16x8 af, bfr;
#pragma unroll
    for (int s = 0; s < 8; ++s) {
      af[s] = (short)f2bf((float)amat(low, quad * 8 + s));
      bfr[s] = (short)f2bf((float)bmatv(pi[quad * 8 + s], low));
    }
    f32x4 d = __builtin_amdgcn_mfma_f32_16x16x32_bf16(af, bfr, zero, 0, 0, 0);
    for (int c = 0; c < 4; ++c) {
      if (cvar >= 0) continue;
      bool match = true;
      for (int r = 0; r < 4; ++r) {
        int rr = (c & 2) ? (r * 4 + quad) : (quad * 4 + r);
        int row = (c & 1) ? low : rr;
        int col = (c & 1) ? rr : low;
        int ref = 0;
        for (int k = 0; k < 32; ++k) ref += amat(row, k) * bmatv(k, col);
        match = match && (d[r] == (float)ref);
      }
      if (__ballot(match) == ~0ull) cvar = c;
    }
  }
  if (lane == 0) flags[2] = ok ? cvar : -1;
  if (ok && lane < 32) flags[8 + lane] = pi[lane];
}

static __device__ __forceinline__ int edge_src(const int* ei, int e, int E,
                                               int i64) {
  return i64 ? ei[2 * (long long)e] : ei[e];
}
static __device__ __forceinline__ int edge_dst(const int* ei, int e, int E,
                                               int i64) {
  return i64 ? ei[2 * ((long long)E + e)] : ei[(long long)E + e];
}

// ---------------- CSR build ----------------

__global__ __launch_bounds__(256) void k_deg(const int* __restrict__ ei, int E,
                                             int N, int* __restrict__ cnt,
                                             const int* __restrict__ flags) {
  int e = blockIdx.x * 256 + threadIdx.x;
  if (e < E) {
    int d = clampN(edge_dst(ei, e, E, flags[1]), N);
    atomicAdd(&cnt[d], 1);
  }
}

__global__ __launch_bounds__(256) void k_scan1(const int* __restrict__ cnt,
                                               int* __restrict__ rowptr,
                                               int* __restrict__ bsum, int N) {
  __shared__ int sh[256];
  int t = threadIdx.x;
  int base = blockIdx.x * 1024 + t * 4;
  int v0 = 0, v1 = 0, v2 = 0, v3 = 0;
  if (base + 0 < N) v0 = cnt[base + 0];
  if (base + 1 < N) v1 = cnt[base + 1];
  if (base + 2 < N) v2 = cnt[base + 2];
  if (base + 3 < N) v3 = cnt[base + 3];
  int s = v0 + v1 + v2 + v3;
  sh[t] = s;
  __syncthreads();
  int acc = s;
  for (int off = 1; off < 256; off <<= 1) {
    int x = 0;
    if (t >= off) x = sh[t - off];
    __syncthreads();
    acc += x;
    sh[t] = acc;
    __syncthreads();
  }
  int run = acc - s;
  if (base + 0 < N) rowptr[base + 0] = run;
  run += v0;
  if (base + 1 < N) rowptr[base + 1] = run;
  run += v1;
  if (base + 2 < N) rowptr[base + 2] = run;
  run += v2;
  if (base + 3 < N) rowptr[base + 3] = run;
  run += v3;
  if (t == 255) bsum[blockIdx.x] = acc;
}

__global__ void k_scan2(int* __restrict__ bsum, int nb,
                        int* __restrict__ rowptr, int N) {
  if (threadIdx.x == 0 && blockIdx.x == 0) {
    int run = 0;
    for (int i = 0; i < nb; ++i) {
      int v = bsum[i];
      bsum[i] = run;
      run += v;
    }
    rowptr[N] = run;
  }
}

__global__ __launch_bounds__(256) void k_scan3(int* __restrict__ rowptr,
                                               int* __restrict__ cursor,
                                               const int* __restrict__ bsum,
                                               int N) {
  int i = blockIdx.x * 256 + threadIdx.x;
  if (i < N) {
    int v = rowptr[i] + bsum[i >> 10];
    rowptr[i] = v;
    cursor[i] = v;
  }
}

__global__ __launch_bounds__(256) void k_scatter(const int* __restrict__ ei,
                                                 int E, int N,
                                                 int* __restrict__ cursor,
                                                 int* __restrict__ colbuf,
                                                 const int* __restrict__ flags) {
  int e = blockIdx.x * 256 + threadIdx.x;
  if (e < E) {
    int i64 = flags[1];
    int s = clampN(edge_src(ei, e, E, i64), N);
    int d = clampN(edge_dst(ei, e, E, i64), N);
    int p = atomicAdd(&cursor[d], 1);
    if (p >= 0 && p < E) colbuf[p] = s;
  }
}

// ---------------- weight transpose into probed MFMA-B order ----------------
// B slot (q,s) must hold W at conv-k pi[q*8+s] so A (filled contig) and B use
// the same effective k convention -> product exact for any true layout.
__global__ __launch_bounds__(256) void k_prepw(const void* Wp, const void* Ws,
                                               unsigned short* __restrict__ WpT,
                                               unsigned short* __restrict__ WsT,
                                               const int* __restrict__ flags) {
  if (!flags[0] || flags[2] < 0) return;
  int o = blockIdx.x * 256 + threadIdx.x;
  const unsigned short* wp = (const unsigned short*)Wp;
  const unsigned short* wsrc = (const unsigned short*)Ws;
  int which = 0;
  int o2 = o;
  if (o >= 24576) {
    which = 1;
    o2 = o - 24576;
    if (o2 >= 4096) return;
  }
  int j = o2 & 7, n = (o2 >> 3) & 15, q = (o2 >> 7) & 3;
  int h = (o2 >> 9) & 1, kb = o2 >> 10;
  int kconv = flags[8 + q * 8 + j];  // probed relative k-map
  if (which == 0)
    WpT[o2] = wp[(kb * 32 + kconv) * 32 + h * 16 + n];
  else
    WsT[o2] = wsrc[(kb * 32 + kconv) * 32 + h * 16 + n];
}

// ---------------- projection ----------------
static __device__ void project_mfma(const unsigned short* __restrict__ xc,
                                    const unsigned short* __restrict__ xs,
                                    const unsigned short* __restrict__ WpT,
                                    const unsigned short* __restrict__ WsT,
                                    const unsigned short* __restrict__ bp,
                                    const unsigned short* __restrict__ bs,
                                    float* __restrict__ h0, int N, int cvar) {
  int gwave = (int)((blockIdx.x * blockDim.x + threadIdx.x) >> 6);
  int lane = (int)(threadIdx.x & 63);
  int m0 = gwave * 16;
  if (m0 >= N) return;
  int n = lane & 15;
  int quad = lane >> 4;

  f32x4 C0 = {0.f, 0.f, 0.f, 0.f}, C1 = {0.f, 0.f, 0.f, 0.f};
  f32x4 S0 = {0.f, 0.f, 0.f, 0.f}, S1 = {0.f, 0.f, 0.f, 0.f};

  const unsigned short* xrow = xc + (long long)(m0 + n) * 768 + quad * 8;
#pragma unroll 4
  for (int kk = 0; kk < 24; ++kk) {
    bf16x8 a = *(const bf16x8*)(xrow + kk * 32);
    bf16x8 b0 = *(const bf16x8*)(WpT + kk * 1024 + quad * 128 + n * 8);
    bf16x8 b1 = *(const bf16x8*)(WpT + kk * 1024 + 512 + quad * 128 + n * 8);
    C0 = __builtin_amdgcn_mfma_f32_16x16x32_bf16(a, b0, C0, 0, 0, 0);
    C1 = __builtin_amdgcn_mfma_f32_16x16x32_bf16(a, b1, C1, 0, 0, 0);
  }
  const unsigned short* srow = xs + (long long)(m0 + n) * 128 + quad * 8;
#pragma unroll
  for (int kk = 0; kk < 4; ++kk) {
    bf16x8 a = *(const bf16x8*)(srow + kk * 32);
    bf16x8 b0 = *(const bf16x8*)(WsT + kk * 1024 + quad * 128 + n * 8);
    bf16x8 b1 = *(const bf16x8*)(WsT + kk * 1024 + 512 + quad * 128 + n * 8);
    S0 = __builtin_amdgcn_mfma_f32_16x16x32_bf16(a, b0, S0, 0, 0, 0);
    S1 = __builtin_amdgcn_mfma_f32_16x16x32_bf16(a, b1, S1, 0, 0, 0);
  }

#pragma unroll
  for (int r = 0; r < 4; ++r) {
    int rr = (cvar & 2) ? (r * 4 + quad) : (quad * 4 + r);
    int node, ff;
    if (cvar & 1) {
      node = m0 + n;
      ff = rr;
    } else {
      node = m0 + rr;
      ff = n;
    }
    float* orow = h0 + (long long)node * 64;
    orow[ff] = C0[r] + bf2f(bp[ff]);
    orow[16 + ff] = C1[r] + bf2f(bp[16 + ff]);
    orow[32 + ff] = S0[r] + bf2f(bs[ff]);
    orow[48 + ff] = S1[r] + bf2f(bs[16 + ff]);
  }
}

template <bool BF>
static __device__ void project_scalar(const void* xc, const void* xs,
                                      const void* Wp, const void* bp,
                                      const void* Ws, const void* bs,
                                      float* __restrict__ h0, int N) {
  int t = (int)threadIdx.x;
  int node = (int)blockIdx.x * 16 + (t >> 4);
  int o2 = (t & 15) * 2;
  if (node >= N) return;
  float c0 = 0.f, c1 = 0.f, s0 = 0.f, s1 = 0.f;
  long long xoff = (long long)node * 768;
#pragma unroll 2
  for (int k = 0; k < 768; k += 8) {
    float xv[8];
    load8<BF>(xc, xoff + k, xv);
#pragma unroll
    for (int j = 0; j < 8; ++j) {
      float w0, w1;
      loadw2<BF>(Wp, (long long)(k + j) * 32 + o2, w0, w1);
      c0 += xv[j] * w0;
      c1 += xv[j] * w1;
    }
  }
  long long soff = (long long)node * 128;
#pragma unroll 2
  for (int k = 0; k < 128; k += 8) {
    float xv[8];
    load8<BF>(xs, soff + k, xv);
#pragma unroll
    for (int j = 0; j < 8; ++j) {
      float w0, w1;
      loadw2<BF>(Ws, (long long)(k + j) * 32 + o2, w0, w1);
      s0 += xv[j] * w0;
      s1 += xv[j] * w1;
    }
  }
  float* orow = h0 + (long long)node * 64;
  orow[o2 + 0] = c0 + ldf<BF>(bp, o2 + 0);
  orow[o2 + 1] = c1 + ldf<BF>(bp, o2 + 1);
  orow[32 + o2 + 0] = s0 + ldf<BF>(bs, o2 + 0);
  orow[32 + o2 + 1] = s1 + ldf<BF>(bs, o2 + 1);
}

// launched with (N+15)/16 blocks — correct grid for BOTH paths.
__global__ __launch_bounds__(256) void k_project(
    const void* xc, const void* xs, const void* Wp, const void* bp,
    const void* Ws, const void* bs, const unsigned short* WpT,
    const unsigned short* WsT, float* h0, int N,
    const int* __restrict__ flags) {
  if (flags[0]) {
    int cvar = flags[2];
    if (cvar >= 0)
      project_mfma((const unsigned short*)xc, (const unsigned short*)xs, WpT,
                   WsT, (const unsigned short*)bp, (const unsigned short*)bs,
                   h0, N, cvar);
    else
      project_scalar<true>(xc, xs, Wp, bp, Ws, bs, h0, N);
  } else {
    project_scalar<false>(xc, xs, Wp, bp, Ws, bs, h0, N);
  }
}

// ---------------- verification + fixup ----------------
template <bool BF>
static __device__ void verify_body(const void* xc, const void* xs,
                                   const void* Wp, const void* bp,
                                   const void* Ws, const void* bs,
                                   const float* __restrict__ h0, int N,
                                   int* flags) {
  int t = (int)threadIdx.x;
  int i = t >> 4;
  int node = i * (N / 16) + (N / 32);
  if (node >= N) node = N - 1;
  int o2 = (t & 15) * 2;
  float c0 = 0.f, c1 = 0.f, s0 = 0.f, s1 = 0.f;
  long long xoff = (long long)node * 768;
  for (int k = 0; k < 768; k += 8) {
    float xv[8];
    load8<BF>(xc, xoff + k, xv);
#pragma unroll
    for (int j = 0; j < 8; ++j) {
      float w0, w1;
      loadw2<BF>(Wp, (long long)(k + j) * 32 + o2, w0, w1);
      c0 += xv[j] * w0;
      c1 += xv[j] * w1;
    }
  }
  long long soff = (long long)node * 128;
  for (int k = 0; k < 128; k += 8) {
    float xv[8];
    load8<BF>(xs, soff + k, xv);
#pragma unroll
    for (int j = 0; j < 8; ++j) {
      float w0, w1;
      loadw2<BF>(Ws, (long long)(k + j) * 32 + o2, w0, w1);
      s0 += xv[j] * w0;
      s1 += xv[j] * w1;
    }
  }
  const float* orow = h0 + (long long)node * 64;
  float r0 = c0 + ldf<BF>(bp, o2 + 0), r1 = c1 + ldf<BF>(bp, o2 + 1);
  float r2 = s0 + ldf<BF>(bs, o2 + 0), r3 = s1 + ldf<BF>(bs, o2 + 1);
  bool bad = fabsf(orow[o2] - r0) > 0.05f || fabsf(orow[o2 + 1] - r1) > 0.05f ||
             fabsf(orow[32 + o2] - r2) > 0.05f ||
             fabsf(orow[33 + o2] - r3) > 0.05f;
  if (bad) atomicOr(&flags[3], 1);
}

__global__ void k_verify(const void* xc, const void* xs, const void* Wp,
                         const void* bp, const void* Ws, const void* bs,
                         const float* h0, int N, int* flags) {
  if (flags[0])
    verify_body<true>(xc, xs, Wp, bp, Ws, bs, h0, N, flags);
  else
    verify_body<false>(xc, xs, Wp, bp, Ws, bs, h0, N, flags);
}

__global__ __launch_bounds__(256) void k_fixup(const void* xc, const void* xs,
                                               const void* Wp, const void* bp,
                                               const void* Ws, const void* bs,
                                               float* h0, int N,
                                               const int* __restrict__ flags) {
  if (!flags[3]) return;
  if (flags[0])
    project_scalar<true>(xc, xs, Wp, bp, Ws, bs, h0, N);
  else
    project_scalar<false>(xc, xs, Wp, bp, Ws, bs, h0, N);
}

// ---------------- SAGE layer ----------------
template <bool BF>
static __device__ void layer_body(const float* __restrict__ hin,
                                  const int* __restrict__ rowptr,
                                  const int* __restrict__ colbuf,
                                  const void* Wl, const void* bl,
                                  const void* Wr, float* __restrict__ hout,
                                  int N, int last, const void* Wo,
                                  const void* bo, void* outp) {
  int node = (int)((blockIdx.x * blockDim.x + threadIdx.x) >> 6);
  int lane = (int)(threadIdx.x & 63);
  if (node >= N) return;
  int rs = rowptr[node], re = rowptr[node + 1];
  float xself = hin[(long long)node * 64 + lane];
  float agg = 0.f;
  for (int cb = rs; cb < re; cb += 64) {
    int sidx = 0;
    if (cb + lane < re) sidx = clampN(colbuf[cb + lane], N);
    int c = re - cb;
    if (c > 64) c = 64;
    for (int t = 0; t < c; ++t) {
      int s = __builtin_amdgcn_readlane(sidx, t);
      agg += hin[(long long)s * 64 + lane];
    }
  }
  int deg = re - rs;
  if (deg > 0) agg *= (1.f / (float)deg);

  float o = ldf<BF>(bl, lane);
#pragma unroll 8
  for (int d = 0; d < 64; ++d) {
    float ad = __uint_as_float(
        __builtin_amdgcn_readlane(__float_as_uint(agg), d));
    float xd = __uint_as_float(
        __builtin_amdgcn_readlane(__float_as_uint(xself), d));
    o += ad * ldf<BF>(Wl, d * 64 + lane);
    o += xd * ldf<BF>(Wr, d * 64 + lane);
  }
  o = fmaxf(o, 0.f);

  if (!last) {
    hout[(long long)node * 64 + lane] = o;
  } else {
    float c0 = o * ldf<BF>(Wo, lane * 2 + 0);
    float c1 = o * ldf<BF>(Wo, lane * 2 + 1);
    for (int off = 32; off > 0; off >>= 1) {
      c0 += __shfl_xor(c0, off, 64);
      c1 += __shfl_xor(c1, off, 64);
    }
    if (lane == 0) {
      float r0 = c0 + ldf<BF>(bo, 0);
      float r1 = c1 + ldf<BF>(bo, 1);
      if (BF) {
        unsigned short* o16 = (unsigned short*)outp;
        o16[(long long)node * 2 + 0] = f2bf(r0);
        o16[(long long)node * 2 + 1] = f2bf(r1);
      } else {
        float* o32 = (float*)outp;
        o32[(long long)node * 2 + 0] = r0;
        o32[(long long)node * 2 + 1] = r1;
      }
    }
  }
}

__global__ __launch_bounds__(256) void k_layer(
    const float* hin, const int* rowptr, const int* colbuf, const void* Wl,
    const void* bl, const void* Wr, float* hout, int N, int last,
    const void* Wo, const void* bo, void* outp, const int* __restrict__ flags) {
  if (flags[0])
    layer_body<true>(hin, rowptr, colbuf, Wl, bl, Wr, hout, N, last, Wo, bo,
                     outp);
  else
    layer_body<false>(hin, rowptr, colbuf, Wl, bl, Wr, hout, N, last, Wo, bo,
                      outp);
}

// ---------------- host ----------------

extern "C" void kernel_launch(void* const* d_in, const int* in_sizes, int n_in,
                              void* d_out, int out_size, void* d_ws,
                              size_t ws_size, hipStream_t stream) {
  const void* xc = d_in[0];
  const void* xs = d_in[1];
  const int* ei = (const int*)d_in[2];
  const void* Wp = d_in[4];
  const void* bp = d_in[5];
  const void* Ws = d_in[6];
  const void* bs = d_in[7];
  const void* Wl1 = d_in[8];
  const void* bl1 = d_in[9];
  const void* Wr1 = d_in[10];
  const void* Wl2 = d_in[11];
  const void* bl2 = d_in[12];
  const void* Wr2 = d_in[13];
  const void* Wl3 = d_in[14];
  const void* bl3 = d_in[15];
  const void* Wr3 = d_in[16];
  const void* Wo = d_in[17];
  const void* bo = d_in[18];

  int N = out_size / 2;   // output is [N, 2]
  int E = in_sizes[3];    // edge_type has E elements

  char* ws = (char*)d_ws;
  size_t off = 0;
  auto alloc = [&](size_t bytes) {
    char* p = ws + off;
    off += (bytes + 255) & ~(size_t)255;
    return p;
  };
  int* flags = (int*)alloc(256);
  unsigned short* WpT = (unsigned short*)alloc(24576 * 2);
  unsigned short* WsT = (unsigned short*)alloc(4096 * 2);
  int* bsum = (int*)alloc(4096);
  int* cnt = (int*)alloc((size_t)N * 4);
  int* rowptr = (int*)alloc((size_t)(N + 1) * 4);
  int* cursor = (int*)alloc((size_t)N * 4);
  int* colbuf = (int*)alloc((size_t)E * 4);
  float* h0 = (float*)alloc((size_t)N * 64 * 4);
  float* h1 = (float*)alloc((size_t)N * 64 * 4);
  (void)ws_size;
  (void)n_in;

  k_detect<<<1, 64, 0, stream>>>(Wp, ei, flags);
  k_cal<<<1, 64, 0, stream>>>(flags);

  hipMemsetAsync(cnt, 0, (size_t)N * 4, stream);
  int eb = (E + 255) / 256;
  k_deg<<<eb, 256, 0, stream>>>(ei, E, N, cnt, flags);
  int sb = (N + 1023) / 1024;
  k_scan1<<<sb, 256, 0, stream>>>(cnt, rowptr, bsum, N);
  k_scan2<<<1, 64, 0, stream>>>(bsum, sb, rowptr, N);
  k_scan3<<<(N + 255) / 256, 256, 0, stream>>>(rowptr, cursor, bsum, N);
  k_scatter<<<eb, 256, 0, stream>>>(ei, E, N, cursor, colbuf, flags);

  k_prepw<<<(24576 + 4096 + 255) / 256, 256, 0, stream>>>(Wp, Ws, WpT, WsT,
                                                          flags);

  int pb = (N + 15) / 16;  // correct grid for BOTH projection paths
  k_project<<<pb, 256, 0, stream>>>(xc, xs, Wp, bp, Ws, bs, WpT, WsT, h0, N,
                                    flags);
  k_verify<<<1, 256, 0, stream>>>(xc, xs, Wp, bp, Ws, bs, h0, N, flags);
  k_fixup<<<pb, 256, 0, stream>>>(xc, xs, Wp, bp, Ws, bs, h0, N, flags);

  int nb4 = (N + 3) / 4;  // 4 waves (nodes) per 256-thread block
  k_layer<<<nb4, 256, 0, stream>>>(h0, rowptr, colbuf, Wl1, bl1, Wr1, h1, N, 0,
                                   nullptr, nullptr, nullptr, flags);
  k_layer<<<nb4, 256, 0, stream>>>(h1, rowptr, colbuf, Wl2, bl2, Wr2, h0, N, 0,
                                   nullptr, nullptr, nullptr, flags);
  k_layer<<<nb4, 256, 0, stream>>>(h0, rowptr, colbuf, Wl3, bl3, Wr3, h1, N, 1,
                                   Wo, bo, d_out, flags);
}